// Round 1
// 1642.379 us; speedup vs baseline: 1.2565x; 1.2565x over previous
//
#include <hip/hip_runtime.h>
#include <hip/hip_bf16.h>
#include <hip/hip_fp16.h>

// Problem constants
// x: (16,64,1024,12) f32, support: (16,3,1024,1024) f32
// out: (16,64,1024,12) f32
#define NB 16
#define V 1024
#define LL 12
#define C64 64
#define SL 3
#define CL 768        // 64*12
#define KTOT 12288    // 12*1024
#define MARKOFF -1e20f

typedef _Float16 f16x8 __attribute__((ext_vector_type(8)));
typedef __attribute__((ext_vector_type(4))) float f32x4;

// fp32 -> fp16 bits (RN). All quantized tensors (x, G, Y, A) are
// small-magnitude; fp16 gives 8x lower rounding error than bf16 at the same
// MFMA rate.
static __device__ __forceinline__ unsigned short f2h(float f) {
  __half h = __float2half(f);
  return __builtin_bit_cast(unsigned short, h);
}

// async global->LDS direct staging, 16B per lane.
// LDS dest must be wave-uniform base + lane*16 (it is: byte offset = t*16).
typedef const __attribute__((address_space(1))) unsigned int gas_u32;
typedef __attribute__((address_space(3))) unsigned int las_u32;
static __device__ __forceinline__ void gld16(const void* g, void* l) {
  __builtin_amdgcn_global_load_lds((gas_u32*)g, (las_u32*)l, 16, 0, 0);
}

// ---------------------------------------------------------------------------
// k_prep: D = F0*W0 (fp32), Gt[(ig*64+o)][c] = fp16( sum_c2 Wf[o,64(i+1)+c2]*Ws[i][c2][64g+c] ),
//         cb[o] = bf[o] + F0*b0 + sum_i F_{i+1}*bs[i]
__global__ __launch_bounds__(256) void k_prep(const float* __restrict__ W0,
                                              const float* __restrict__ b0,
                                              const float* __restrict__ Ws,
                                              const float* __restrict__ bs,
                                              const float* __restrict__ Wf,
                                              const float* __restrict__ bf,
                                              float* __restrict__ D,
                                              float* __restrict__ cb,
                                              unsigned short* __restrict__ Gt) {
  int b = blockIdx.x;
  int t = threadIdx.x;
  int o = t >> 2, cp = t & 3;
  if (b < 12) {
    int i = b >> 2, g = b & 3;
    for (int c = cp * 16; c < cp * 16 + 16; c++) {
      float acc = 0.f;
      for (int c2 = 0; c2 < 64; c2++)
        acc += Wf[o * 256 + 64 * (i + 1) + c2] * Ws[i * 16384 + c2 * 256 + g * 64 + c];
      Gt[(size_t)(b * 64 + o) * 64 + c] = f2h(acc);
    }
  } else {
    for (int c = cp * 16; c < cp * 16 + 16; c++) {
      float acc = 0.f;
      for (int c2 = 0; c2 < 64; c2++)
        acc += Wf[o * 256 + c2] * W0[c2 * 64 + c];
      D[o * 64 + c] = acc;
    }
    if (t < 64) {
      float acc = bf[t];
      for (int c2 = 0; c2 < 64; c2++) acc += Wf[t * 256 + c2] * b0[c2];
      for (int i = 0; i < 3; i++)
        for (int c2 = 0; c2 < 64; c2++) acc += Wf[t * 256 + 64 * (i + 1) + c2] * bs[i * 64 + c2];
      cb[t] = acc;
    }
  }
}

// ---------------------------------------------------------------------------
// k_stats: per row (n,i,v) of support, stride-12 stats:
// {m, 1/Zf, T10, T20, T40, 1/Z10, 1/Z20, 1/Z40, wcut10, wcut20, wcut40, pad}
// T_k exact k-th largest (radix select). Tie handling matches jax.lax.top_k
// (lowest index first): admit elements > T_k plus the r = k - cnt_gt
// lowest-indexed elements == T_k; wcut = index of the r-th such element.
__global__ __launch_bounds__(256) void k_stats(const float* __restrict__ support,
                                               float* __restrict__ stats) {
  int row = blockIdx.x;  // (n*3+i)*1024 + v
  const float* a = support + (size_t)row * 1024;
  int t = threadIdx.x;
  int lane = t & 63, wid = t >> 6;

  float va[4];
  unsigned ky[4];
#pragma unroll
  for (int j = 0; j < 4; j++) va[j] = a[t + 256 * j];

  __shared__ float sred[8];
  __shared__ float s4[4][4];
  __shared__ unsigned hist[64];
  __shared__ unsigned ssel[3];
  __shared__ unsigned smax;
  __shared__ unsigned scnt;
  __shared__ unsigned sbest;
  __shared__ unsigned swcut[3];
  __shared__ unsigned sr[3];

  // row max
  float m = fmaxf(fmaxf(va[0], va[1]), fmaxf(va[2], va[3]));
#pragma unroll
  for (int off = 32; off; off >>= 1) m = fmaxf(m, __shfl_xor(m, off));
  if (lane == 0) sred[wid] = m;
  __syncthreads();
  if (t == 0) sred[4] = fmaxf(fmaxf(sred[0], sred[1]), fmaxf(sred[2], sred[3]));
  __syncthreads();
  m = sred[4];

#pragma unroll
  for (int j = 0; j < 4; j++) {
    unsigned u = __float_as_uint(va[j]);
    ky[j] = (u & 0x80000000u) ? ~u : (u | 0x80000000u);
  }

  float T[3];
  const int kks[3] = {10, 20, 40};
  const int shifts[6] = {26, 20, 14, 8, 2, 0};
  for (int s3 = 0; s3 < 3; s3++) {
    unsigned prefix = 0, resolved = 0, tkey = 0;
    int r = kks[s3];
    bool done = false;
    for (int p = 0; p < 6 && !done; p++) {
      int sh = shifts[p];
      int width = (p == 5) ? 2 : 6;
      unsigned wmask = (1u << width) - 1u;
      if (t < 64) hist[t] = 0u;
      __syncthreads();
#pragma unroll
      for (int j = 0; j < 4; j++)
        if ((ky[j] & resolved) == prefix) atomicAdd(&hist[(ky[j] >> sh) & wmask], 1u);
      __syncthreads();
      if (t < 64) {
        int bins = 1 << width;
        unsigned h = (t < bins) ? hist[(bins - 1) - t] : 0u;
        unsigned cum = h;
#pragma unroll
        for (int off = 1; off < 64; off <<= 1) {
          unsigned v2 = __shfl_up(cum, off);
          if (t >= off) cum += v2;
        }
        unsigned long long bal = __ballot(cum >= (unsigned)r);
        int sl = __ffsll(bal) - 1;
        if (t == sl) {
          unsigned dsel = (unsigned)((bins - 1) - sl);
          ssel[0] = prefix | (dsel << sh);
          ssel[1] = (unsigned)r - (cum - h);
          ssel[2] = h;
        }
      }
      __syncthreads();
      prefix = ssel[0];
      r = (int)ssel[1];
      unsigned cnt = ssel[2];
      resolved |= (wmask << sh);
      __syncthreads();
      if (cnt == 1u && p < 5) {
        if (t == 0) smax = 0u;
        __syncthreads();
#pragma unroll
        for (int j = 0; j < 4; j++)
          if ((ky[j] & resolved) == prefix) atomicMax(&smax, ky[j]);
        __syncthreads();
        tkey = smax;
        done = true;
      }
    }
    if (!done) tkey = prefix;
    unsigned u2 = (tkey & 0x80000000u) ? (tkey & 0x7FFFFFFFu) : ~tkey;
    float Tcur = __uint_as_float(u2);
    T[s3] = Tcur;

    // --- exact tie handling (match top_k's lowest-index-first) ---
    if (t == 0) scnt = 0u;
    __syncthreads();
    unsigned mygt = 0;
#pragma unroll
    for (int j = 0; j < 4; j++)
      if (va[j] > Tcur) mygt++;
    if (mygt) atomicAdd(&scnt, mygt);
    __syncthreads();
    int radm = kks[s3] - (int)scnt;  // #tied elements admitted, >= 1
    unsigned prev = 0xFFFFFFFFu;
    for (int it = 0; it < radm; it++) {
      if (t == 0) sbest = 0xFFFFFFFFu;
      __syncthreads();
#pragma unroll
      for (int j = 0; j < 4; j++) {
        unsigned idx = (unsigned)(t + 256 * j);
        if (va[j] == Tcur && (it == 0 || idx > prev)) atomicMin(&sbest, idx);
      }
      __syncthreads();
      prev = sbest;
      __syncthreads();
    }
    if (t == 0) { swcut[s3] = prev; sr[s3] = (unsigned)radm; }
    __syncthreads();
  }

  // exp sums (strictly-greater partial sums; tied mass added analytically)
  float zf = 0.f, z40 = 0.f, z20 = 0.f, z10 = 0.f;
#pragma unroll
  for (int j = 0; j < 4; j++) {
    float ee = __expf(va[j] - m);
    zf += ee;
    if (va[j] > T[2]) z40 += ee;
    if (va[j] > T[1]) z20 += ee;
    if (va[j] > T[0]) z10 += ee;
  }
#pragma unroll
  for (int off = 32; off; off >>= 1) {
    zf += __shfl_xor(zf, off);
    z40 += __shfl_xor(z40, off);
    z20 += __shfl_xor(z20, off);
    z10 += __shfl_xor(z10, off);
  }
  if (lane == 0) {
    s4[wid][0] = zf; s4[wid][1] = z40; s4[wid][2] = z20; s4[wid][3] = z10;
  }
  __syncthreads();
  if (t == 0) {
    float a0 = 0, a1 = 0, a2 = 0, a3 = 0;
    for (int wq = 0; wq < 4; wq++) { a0 += s4[wq][0]; a1 += s4[wq][1]; a2 += s4[wq][2]; a3 += s4[wq][3]; }
    float Z10 = a3 + (float)sr[0] * __expf(T[0] - m);
    float Z20 = a2 + (float)sr[1] * __expf(T[1] - m);
    float Z40 = a1 + (float)sr[2] * __expf(T[2] - m);
    float* sp = stats + (size_t)row * 12;
    sp[0] = m;
    sp[1] = 1.f / a0;
    sp[2] = T[0];
    sp[3] = T[1];
    sp[4] = T[2];
    sp[5] = 1.f / Z10;
    sp[6] = 1.f / Z20;
    sp[7] = 1.f / Z40;
    sp[8] = (float)swcut[0];
    sp[9] = (float)swcut[1];
    sp[10] = (float)swcut[2];
    sp[11] = 0.f;
  }
}

// ---------------------------------------------------------------------------
// k_init: out[n,o,w,l] = cb[o] + sum_c D[o,c] * x[n,c,w,l]   (fp32 direct path)
__global__ __launch_bounds__(256) void k_init(const float* __restrict__ x,
                                              const float* __restrict__ D,
                                              const float* __restrict__ cb,
                                              float* __restrict__ out) {
  int b = blockIdx.x;
  int n = b >> 10, w = b & 1023;
  int t = threadIdx.x;
  __shared__ float xs[768];
  __shared__ float Ds[64 * 65];
  __shared__ float cbs[64];
  const float* xb = x + (size_t)n * 786432 + w * 12;
  for (int u = t; u < 768; u += 256) {
    int c = u / 12, l2 = u - c * 12;
    xs[u] = xb[(size_t)c * 12288 + l2];
  }
  for (int u = t; u < 4096; u += 256) Ds[(u >> 6) * 65 + (u & 63)] = D[u];
  if (t < 64) cbs[t] = cb[t];
  __syncthreads();
  float* ob = out + (size_t)n * 786432 + w * 12;
  for (int u = t; u < 768; u += 256) {
    int o = u / 12, l2 = u - o * 12;
    float accv = cbs[o];
    const float* dr = &Ds[o * 65];
#pragma unroll
    for (int c = 0; c < 64; c++) accv += dr[c] * xs[c * 12 + l2];
    ob[(size_t)o * 12288 + l2] = accv;
  }
}

// ---------------------------------------------------------------------------
// k_ybuild: Y[(o*12+l)*12288 + ig*1024 + v] = fp16( sum_c x[n,c,v,l] * G[ig][o][c] )
__global__ __launch_bounds__(256) void k_ybuild(const float* __restrict__ x,
                                                const unsigned short* __restrict__ Gt,
                                                unsigned short* __restrict__ Y,
                                                int s) {
  int b = blockIdx.x;
  int nc = b / 576;
  int rem2 = b - nc * 576;
  int mt = rem2 / 6, nt = rem2 - (rem2 / 6) * 6;
  int n = s + nc;
  int l = mt >> 3;
  int v0 = (mt & 7) << 7;

  __shared__ __align__(16) char smem[34816];
  unsigned short(*A2)[128][32] = (unsigned short(*)[128][32])smem;
  unsigned short(*B2)[128][32] = (unsigned short(*)[128][32])(smem + 16384);
  unsigned short(*R)[136] = (unsigned short(*)[136])smem;

  int t = threadIdx.x;
  int lane = t & 63, wid = t >> 6;
  int wm = (wid >> 1) * 64, wn = (wid & 1) * 64;

  // stage A: x[n][c][v0+mloc][l] for c in [half*32, half*32+32)
  {
    int mloc = t >> 1, half = t & 1;
    const float* xp = x + (size_t)n * 786432 + (size_t)(half * 32) * 12288 + (size_t)(v0 + mloc) * 12 + l;
#pragma unroll
    for (int sg = 0; sg < 4; sg++) {
      unsigned q0 = f2h(xp[(size_t)(sg * 8 + 0) * 12288]) | ((unsigned)f2h(xp[(size_t)(sg * 8 + 1) * 12288]) << 16);
      unsigned q1 = f2h(xp[(size_t)(sg * 8 + 2) * 12288]) | ((unsigned)f2h(xp[(size_t)(sg * 8 + 3) * 12288]) << 16);
      unsigned q2 = f2h(xp[(size_t)(sg * 8 + 4) * 12288]) | ((unsigned)f2h(xp[(size_t)(sg * 8 + 5) * 12288]) << 16);
      unsigned q3 = f2h(xp[(size_t)(sg * 8 + 6) * 12288]) | ((unsigned)f2h(xp[(size_t)(sg * 8 + 7) * 12288]) << 16);
      uint4 q = {q0, q1, q2, q3};
      *(uint4*)&A2[half][mloc][sg * 8] = q;
    }
  }
  // stage B: Gt rows nt*128..+128
  {
    int row = t >> 1, half = t & 1;
    const unsigned short* gp = Gt + (size_t)(nt * 128 + row) * 64 + half * 32;
#pragma unroll
    for (int sg = 0; sg < 4; sg++)
      *(uint4*)&B2[half][row][sg * 8] = *(const uint4*)(gp + sg * 8);
  }
  __syncthreads();

  f32x4 acc[4][4];
#pragma unroll
  for (int fm = 0; fm < 4; fm++)
#pragma unroll
    for (int fn = 0; fn < 4; fn++) acc[fm][fn] = (f32x4){0.f, 0.f, 0.f, 0.f};

  int ko = (lane >> 4) * 8;
#pragma unroll
  for (int half = 0; half < 2; half++) {
    f16x8 af[4], bfr[4];
#pragma unroll
    for (int fm = 0; fm < 4; fm++) af[fm] = *(const f16x8*)&A2[half][wm + fm * 16 + (lane & 15)][ko];
#pragma unroll
    for (int fn = 0; fn < 4; fn++) bfr[fn] = *(const f16x8*)&B2[half][wn + fn * 16 + (lane & 15)][ko];
#pragma unroll
    for (int fm = 0; fm < 4; fm++)
#pragma unroll
      for (int fn = 0; fn < 4; fn++)
        acc[fm][fn] = __builtin_amdgcn_mfma_f32_16x16x32_f16(af[fm], bfr[fn], acc[fm][fn], 0, 0, 0);
  }
  __syncthreads();

  // reorder into R[col][m] (m = v offset), 4 consecutive rows per frag-reg
#pragma unroll
  for (int fm = 0; fm < 4; fm++)
#pragma unroll
    for (int fn = 0; fn < 4; fn++) {
      int col = wn + fn * 16 + (lane & 15);
      int mrow = wm + fm * 16 + (lane >> 4) * 4;
      unsigned lo = (unsigned)f2h(acc[fm][fn][0]) | ((unsigned)f2h(acc[fm][fn][1]) << 16);
      unsigned hi = (unsigned)f2h(acc[fm][fn][2]) | ((unsigned)f2h(acc[fm][fn][3]) << 16);
      uint2 pk = {lo, hi};
      *(uint2*)&R[col][mrow] = pk;
    }
  __syncthreads();

  // coalesced output: row = ncol-local, 128 v contiguous
  {
    int row = t >> 1, hseg = t & 1;
    int ncol = nt * 128 + row;
    int ig = ncol >> 6, o = ncol & 63;
    size_t gbase = ((size_t)nc * 768 + (size_t)(o * 12 + l)) * 12288 + (size_t)ig * 1024 + v0 + hseg * 64;
#pragma unroll
    for (int sg = 0; sg < 8; sg++)
      *(uint4*)(Y + gbase + sg * 8) = *(const uint4*)&R[row][hseg * 64 + sg * 8];
  }
}

// ---------------------------------------------------------------------------
// k_buildA: A[(nc*1024+w)*12288 + i*4096 + g*1024 + v] = fp16 softmax weights
__global__ __launch_bounds__(256) void k_buildA(const float* __restrict__ support,
                                                const float* __restrict__ stats,
                                                unsigned short* __restrict__ Abuf,
                                                int s) {
  int b = blockIdx.x;
  int nc = b / 3072;
  int rem2 = b - nc * 3072;
  int i = rem2 >> 10;
  int tile = rem2 & 1023;
  int v0 = (tile >> 5) << 5;
  int w0 = (tile & 31) << 5;
  int n = s + nc;
  const float* sup = support + (size_t)(n * 3 + i) * 1024 * 1024;
  const float* stb = stats + (size_t)(n * 3 + i) * 1024 * 12;

  __shared__ float S[32][33];
  __shared__ float st[32][12];
  int t = threadIdx.x;
  {
    int vl = t >> 3, wseg = t & 7;
    const float* p = sup + (size_t)(v0 + vl) * 1024 + w0 + wseg * 4;
    float4 f = *(const float4*)p;
    S[vl][wseg * 4 + 0] = f.x;
    S[vl][wseg * 4 + 1] = f.y;
    S[vl][wseg * 4 + 2] = f.z;
    S[vl][wseg * 4 + 3] = f.w;
  }
  for (int u = t; u < 384; u += 256) {
    int vl = u / 12, q = u - vl * 12;
    st[vl][q] = stb[(size_t)(v0 + vl) * 12 + q];
  }
  __syncthreads();

  int w_loc = t >> 3, vseg = t & 7;
  float wg = (float)(w0 + w_loc);
  unsigned short bv[4][4];
#pragma unroll
  for (int j = 0; j < 4; j++) {
    int vl = vseg * 4 + j;
    float aa = S[vl][w_loc];
    float m = st[vl][0], izf = st[vl][1];
    float T10 = st[vl][2], T20 = st[vl][3], T40 = st[vl][4];
    float iz10 = st[vl][5], iz20 = st[vl][6], iz40 = st[vl][7];
    float w10 = st[vl][8], w20 = st[vl][9], w40 = st[vl][10];
    float ee = __expf(aa - m);
    bool in10 = (aa > T10) || (aa == T10 && wg <= w10);
    bool in20 = (aa > T20) || (aa == T20 && wg <= w20);
    bool in40 = (aa > T40) || (aa == T40 && wg <= w40);
    bv[3][j] = f2h(ee * izf);
    bv[2][j] = f2h(in40 ? ee * iz40 : 0.f);
    bv[1][j] = f2h(in20 ? ee * iz20 : 0.f);
    bv[0][j] = f2h(in10 ? ee * iz10 : 0.f);
  }
  size_t base = ((size_t)nc * 1024 + w0 + w_loc) * 12288 + (size_t)i * 4096 + v0 + vseg * 4;
#pragma unroll
  for (int g = 0; g < 4; g++) {
    uint2 pk;
    pk.x = (unsigned)bv[g][0] | ((unsigned)bv[g][1] << 16);
    pk.y = (unsigned)bv[g][2] | ((unsigned)bv[g][3] << 16);
    *(uint2*)(Abuf + base + (size_t)g * 1024) = pk;
  }
}

// ---------------------------------------------------------------------------
// k_biggemm: OUT[n][w][(o,l)] += sum_k A[w][k] * Y[(o,l)][k]; M=1024, N=768, K=12288
// m97-structure: global_load_lds width-16 direct staging (no reg round-trip,
// no ds_write bank conflicts), 2 barriers per K-step, + XCD-aware block swizzle.
__global__ __launch_bounds__(256) void k_biggemm(const unsigned short* __restrict__ A,
                                                 const unsigned short* __restrict__ Y,
                                                 float* __restrict__ out,
                                                 int s) {
  // XCD swizzle: grid = Cc*48, always % 8 == 0 -> simple bijective remap.
  // Each XCD gets a contiguous run of tiles so same-n A/Y panels are shared
  // through that XCD's private L2 instead of re-fetched from HBM.
  int b = blockIdx.x;
  int cpx = gridDim.x >> 3;
  b = (b & 7) * cpx + (b >> 3);

  int nc = b / 48;
  int rem2 = b - nc * 48;
  int mt = rem2 / 6, nt = rem2 - (rem2 / 6) * 6;
  int n = s + nc;

  __shared__ __align__(16) unsigned short A3[128][32];
  __shared__ __align__(16) unsigned short B3[128][32];

  int t = threadIdx.x;
  int lane = t & 63, wid = t >> 6;
  int wm = (wid >> 1) * 64, wn = (wid & 1) * 64;

  const unsigned short* Ab = A + (size_t)nc * 12582912 + (size_t)(mt * 128) * 12288;
  const unsigned short* Yb = Y + (size_t)nc * 9437184 + (size_t)(nt * 128) * 12288;

  // staging map: thread t carries one 16B chunk; row = t>>2 (and +64 for the
  // second issue), col elements (t&3)*8. Linear LDS offset = t*16 bytes, which
  // is exactly the wave-uniform-base + lane*16 order global_load_lds writes.
  int srow = t >> 2;
  int scol = (t & 3) * 8;
  const unsigned short* gA0 = Ab + (size_t)srow * 12288 + scol;
  const unsigned short* gA1 = gA0 + (size_t)64 * 12288;
  const unsigned short* gB0 = Yb + (size_t)srow * 12288 + scol;
  const unsigned short* gB1 = gB0 + (size_t)64 * 12288;
  unsigned short* lA0 = &A3[0][0] + (size_t)t * 8;
  unsigned short* lA1 = lA0 + 2048;
  unsigned short* lB0 = &B3[0][0] + (size_t)t * 8;
  unsigned short* lB1 = lB0 + 2048;

  f32x4 acc[4][4];
#pragma unroll
  for (int fm = 0; fm < 4; fm++)
#pragma unroll
    for (int fn = 0; fn < 4; fn++) acc[fm][fn] = (f32x4){0.f, 0.f, 0.f, 0.f};

  int ko = (lane >> 4) * 8;

  for (int kt = 0; kt < 384; kt++) {
    __syncthreads();  // previous step's ds_reads done before DMA overwrites LDS
    gld16(gA0, lA0);
    gld16(gA1, lA1);
    gld16(gB0, lB0);
    gld16(gB1, lB1);
    gA0 += 32; gA1 += 32; gB0 += 32; gB1 += 32;
    __syncthreads();  // compiler emits vmcnt(0) drain before s_barrier -> tile ready
    f16x8 af[4], bfr[4];
#pragma unroll
    for (int fm = 0; fm < 4; fm++) af[fm] = *(const f16x8*)&A3[wm + fm * 16 + (lane & 15)][ko];
#pragma unroll
    for (int fn = 0; fn < 4; fn++) bfr[fn] = *(const f16x8*)&B3[wn + fn * 16 + (lane & 15)][ko];
#pragma unroll
    for (int fm = 0; fm < 4; fm++)
#pragma unroll
      for (int fn = 0; fn < 4; fn++)
        acc[fm][fn] = __builtin_amdgcn_mfma_f32_16x16x32_f16(af[fm], bfr[fn], acc[fm][fn], 0, 0, 0);
  }

  // epilogue: RMW into out (tiles are exclusive)
  float* ob = out + (size_t)n * 786432;
#pragma unroll
  for (int fn = 0; fn < 4; fn++) {
    int col = nt * 128 + wn + fn * 16 + (lane & 15);  // = o*12 + l
    int oo = col / 12;
    int ll2 = col - oo * 12;
    float* cbase = ob + (size_t)oo * 12288 + ll2;
#pragma unroll
    for (int fm = 0; fm < 4; fm++) {
      int w = mt * 128 + wm + fm * 16 + (lane >> 4) * 4;
      float* p = cbase + (size_t)w * 12;
#pragma unroll
      for (int r = 0; r < 4; r++) p[r * 12] += acc[fm][fn][r];
    }
  }
}

// ---------------------------------------------------------------------------
extern "C" void kernel_launch(void* const* d_in, const int* in_sizes, int n_in,
                              void* d_out, int out_size, void* d_ws, size_t ws_size,
                              hipStream_t stream) {
  const float* x = (const float*)d_in[0];
  const float* support = (const float*)d_in[1];
  const float* W0 = (const float*)d_in[2];
  const float* b0 = (const float*)d_in[3];
  const float* Ws = (const float*)d_in[4];
  const float* bs = (const float*)d_in[5];
  const float* Wf = (const float*)d_in[6];
  const float* bf = (const float*)d_in[7];
  float* out = (float*)d_out;
  char* ws = (char*)d_ws;

  float* stats = (float*)ws;                              // 49152*12*4 = 2,359,296 B
  float* D = (float*)(ws + 2359296);                      // 16,384 B
  float* cb = (float*)(ws + 2375680);                     // 256 B
  unsigned short* Gt = (unsigned short*)(ws + 2375936);   // 98,304 B
  const size_t fixed_end = 2474240;
  const size_t szY = 18874368;  // per n
  const size_t szA = 25165824;  // per n

  int C = 1;
  if (ws_size > fixed_end) {
    size_t remb = ws_size - fixed_end;
    size_t c = remb / (szY + szA);
    if (c > 16) c = 16;
    if (c < 1) c = 1;
    C = (int)c;
  }
  unsigned short* Ybuf = (unsigned short*)(ws + fixed_end);
  unsigned short* Abuf = (unsigned short*)(ws + fixed_end + (size_t)C * szY);

  k_prep<<<13, 256, 0, stream>>>(W0, b0, Ws, bs, Wf, bf, D, cb, Gt);
  k_stats<<<49152, 256, 0, stream>>>(support, stats);
  k_init<<<16384, 256, 0, stream>>>(x, D, cb, out);
  for (int s = 0; s < 16; s += C) {
    int Cc = (16 - s) < C ? (16 - s) : C;
    k_ybuild<<<Cc * 576, 256, 0, stream>>>(x, Gt, Ybuf, s);
    k_buildA<<<Cc * 3072, 256, 0, stream>>>(support, stats, Abuf, s);
    k_biggemm<<<Cc * 48, 256, 0, stream>>>(Abuf, Ybuf, out, s);
  }
}

// Round 2
// 1179.411 us; speedup vs baseline: 1.7498x; 1.3925x over previous
//
#include <hip/hip_runtime.h>
#include <hip/hip_bf16.h>
#include <hip/hip_fp16.h>

// Problem constants
// x: (16,64,1024,12) f32, support: (16,3,1024,1024) f32
// out: (16,64,1024,12) f32
#define NB 16
#define V 1024
#define LL 12
#define C64 64
#define SL 3
#define CL 768        // 64*12
#define KTOT 12288    // 12*1024
#define MARKOFF -1e20f

typedef _Float16 f16x8 __attribute__((ext_vector_type(8)));
typedef __attribute__((ext_vector_type(4))) float f32x4;

// fp32 -> fp16 bits (RN). All quantized tensors (x, G, Y, A) are
// small-magnitude; fp16 gives 8x lower rounding error than bf16 at the same
// MFMA rate.
static __device__ __forceinline__ unsigned short f2h(float f) {
  __half h = __float2half(f);
  return __builtin_bit_cast(unsigned short, h);
}

// async global->LDS direct staging, 16B per lane.
// LDS dest must be wave-uniform base + lane*16 (it is: byte offset = t*16).
typedef const __attribute__((address_space(1))) unsigned int gas_u32;
typedef __attribute__((address_space(3))) unsigned int las_u32;
static __device__ __forceinline__ void gld16(const void* g, void* l) {
  __builtin_amdgcn_global_load_lds((gas_u32*)g, (las_u32*)l, 16, 0, 0);
}

// 64-bit cross-lane helpers (2x32-bit shuffles)
static __device__ __forceinline__ unsigned long long shflx64(unsigned long long v, int m) {
  unsigned lo = __shfl_xor((unsigned)v, m);
  unsigned hi = __shfl_xor((unsigned)(v >> 32), m);
  return ((unsigned long long)hi << 32) | lo;
}
static __device__ __forceinline__ unsigned long long shfl64get(unsigned long long v, int srcLane) {
  unsigned lo = __shfl((unsigned)v, srcLane);
  unsigned hi = __shfl((unsigned)(v >> 32), srcLane);
  return ((unsigned long long)hi << 32) | lo;
}
// monotone key <-> float
static __device__ __forceinline__ float k2f(unsigned kk) {
  unsigned u = (kk & 0x80000000u) ? (kk & 0x7FFFFFFFu) : ~kk;
  return __uint_as_float(u);
}

// ---------------------------------------------------------------------------
// k_prep: D = F0*W0 (fp32), Gt[(ig*64+o)][c] = fp16( sum_c2 Wf[o,64(i+1)+c2]*Ws[i][c2][64g+c] ),
//         cb[o] = bf[o] + F0*b0 + sum_i F_{i+1}*bs[i]
__global__ __launch_bounds__(256) void k_prep(const float* __restrict__ W0,
                                              const float* __restrict__ b0,
                                              const float* __restrict__ Ws,
                                              const float* __restrict__ bs,
                                              const float* __restrict__ Wf,
                                              const float* __restrict__ bf,
                                              float* __restrict__ D,
                                              float* __restrict__ cb,
                                              unsigned short* __restrict__ Gt) {
  int b = blockIdx.x;
  int t = threadIdx.x;
  int o = t >> 2, cp = t & 3;
  if (b < 12) {
    int i = b >> 2, g = b & 3;
    for (int c = cp * 16; c < cp * 16 + 16; c++) {
      float acc = 0.f;
      for (int c2 = 0; c2 < 64; c2++)
        acc += Wf[o * 256 + 64 * (i + 1) + c2] * Ws[i * 16384 + c2 * 256 + g * 64 + c];
      Gt[(size_t)(b * 64 + o) * 64 + c] = f2h(acc);
    }
  } else {
    for (int c = cp * 16; c < cp * 16 + 16; c++) {
      float acc = 0.f;
      for (int c2 = 0; c2 < 64; c2++)
        acc += Wf[o * 256 + c2] * W0[c2 * 64 + c];
      D[o * 64 + c] = acc;
    }
    if (t < 64) {
      float acc = bf[t];
      for (int c2 = 0; c2 < 64; c2++) acc += Wf[t * 256 + c2] * b0[c2];
      for (int i = 0; i < 3; i++)
        for (int c2 = 0; c2 < 64; c2++) acc += Wf[t * 256 + 64 * (i + 1) + c2] * bs[i * 64 + c2];
      cb[t] = acc;
    }
  }
}

// ---------------------------------------------------------------------------
// k_stats v2: ONE WAVE PER ROW, barrier-light, atomic-free, histogram-free.
// Per row (n,i,v) of support, stride-12 stats:
// {m, 1/Zf, T10, T20, T40, 1/Z10, 1/Z20, 1/Z40, wcut10, wcut20, wcut40, pad}
// Method: pivot via count-binary-search (seed 1.4 -> E[count]=83 for N(0,1)),
// compact <=128 survivors as u64 (key32(val) : ~idx) into wave-private LDS,
// bitonic sort (desc) in registers via shfl_xor. Sorted order == top_k order
// (value desc, lowest index first on ties), so element k-1 yields T_k and
// wcut_k, and lanes 0..k-1 yield Z_k directly.
__global__ __launch_bounds__(256) void k_stats(const float* __restrict__ support,
                                               float* __restrict__ stats) {
  int t = threadIdx.x;
  int lane = t & 63, wid = t >> 6;
  int row = blockIdx.x * 4 + wid;  // (n*3+i)*1024 + v
  const float* a = support + (size_t)row * 1024;

  __shared__ unsigned long long cand[4][128];

  // load 16 values per lane, coalesced float4; idx(q) = lane*4 + (q>>2)*256 + (q&3)
  float va[16];
  const float4* a4 = (const float4*)a;
#pragma unroll
  for (int j = 0; j < 4; j++) {
    float4 f = a4[lane + 64 * j];
    va[j * 4 + 0] = f.x; va[j * 4 + 1] = f.y; va[j * 4 + 2] = f.z; va[j * 4 + 3] = f.w;
  }

  // row max
  float m = va[0];
#pragma unroll
  for (int q = 1; q < 16; q++) m = fmaxf(m, va[q]);
#pragma unroll
  for (int off = 32; off; off >>= 1) m = fmaxf(m, __shfl_xor(m, off));

  // full softmax denominator
  float zf = 0.f;
#pragma unroll
  for (int q = 0; q < 16; q++) zf += __expf(va[q] - m);
#pragma unroll
  for (int off = 32; off; off >>= 1) zf += __shfl_xor(zf, off);

  // monotone keys
  unsigned ky[16];
#pragma unroll
  for (int q = 0; q < 16; q++) {
    unsigned u = __float_as_uint(va[q]);
    ky[q] = (u & 0x80000000u) ? ~u : (u | 0x80000000u);
  }

  // find pivot K with 40 <= count(key > K) <= 128 (wave-uniform search)
  unsigned Klo = 0u, Khi = 0xFFFFFFFFu;
  unsigned K = 0xBFB33333u;  // key(1.4f) seed
  int c = 0;
  bool ok = false;
  for (int it = 0; it < 40; ++it) {
    int cl = 0;
#pragma unroll
    for (int q = 0; q < 16; q++) cl += (ky[q] > K) ? 1 : 0;
    c = cl;
#pragma unroll
    for (int off = 32; off; off >>= 1) c += __shfl_xor(c, off);
    if (c >= 40 && c <= 128) { ok = true; break; }
    if (c > 128) Klo = K; else Khi = K;
    if (Khi - Klo <= 1u) break;
    K = Klo + ((Khi - Klo) >> 1);
  }
  bool special = !ok;  // giant tie cluster at key Khi (never on continuous data)
  if (special) {
    K = Khi;  // candidates are strictly-greater than the cluster key; c < 40
    int cl = 0;
#pragma unroll
    for (int q = 0; q < 16; q++) cl += (ky[q] > K) ? 1 : 0;
    c = cl;
#pragma unroll
    for (int off = 32; off; off >>= 1) c += __shfl_xor(c, off);
  }

  // compact survivors to wave-private LDS as (key<<32 | ~idx), pad with 0
  int cl = 0;
#pragma unroll
  for (int q = 0; q < 16; q++) cl += (ky[q] > K) ? 1 : 0;
  int pre = cl;
#pragma unroll
  for (int off = 1; off < 64; off <<= 1) {
    int t2 = __shfl_up(pre, off);
    if (lane >= off) pre += t2;
  }
  int o = pre - cl;  // exclusive prefix
  cand[wid][lane] = 0ull;
  cand[wid][64 + lane] = 0ull;
  __syncthreads();
#pragma unroll
  for (int q = 0; q < 16; q++) {
    if (ky[q] > K) {
      unsigned idx = (unsigned)(lane * 4 + (q >> 2) * 256 + (q & 3));
      cand[wid][o++] = ((unsigned long long)ky[q] << 32) | (unsigned)(~idx);
    }
  }
  __syncthreads();
  unsigned long long s0 = cand[wid][lane];        // element e = lane
  unsigned long long s1 = cand[wid][64 + lane];   // element e = 64 + lane

  // bitonic sort, 128 elements, DESCENDING by (value, then lowest idx first)
#pragma unroll
  for (int k2 = 2; k2 <= 128; k2 <<= 1) {
#pragma unroll
    for (int j = k2 >> 1; j > 0; j >>= 1) {
      if (j == 64) {
        // cross-register, same lane; k2==128 -> descending everywhere
        unsigned long long mx = (s0 > s1) ? s0 : s1;
        unsigned long long mn = (s0 > s1) ? s1 : s0;
        s0 = mx; s1 = mn;
      } else {
        bool lower = ((lane & j) == 0);
        bool d0 = ((lane & k2) == 0);          // e = lane
        bool d1 = (((64 + lane) & k2) == 0);   // e = 64+lane
        unsigned long long q0 = shflx64(s0, j);
        unsigned long long q1 = shflx64(s1, j);
        bool kmax0 = (lower == d0);
        bool kmax1 = (lower == d1);
        s0 = (kmax0 == (s0 > q0)) ? s0 : q0;
        s1 = (kmax1 == (s1 > q1)) ? s1 : q1;
      }
    }
  }

  // per-lane exp of sorted candidate (lanes 0..min(c,40)-1 are real)
  int nval = (c < 40) ? c : 40;
  float pv = 0.f;
  if (lane < nval) pv = __expf(k2f((unsigned)(s0 >> 32)) - m);
  float z10 = (lane < 10) ? pv : 0.f;
  float z20 = (lane < 20) ? pv : 0.f;
  float z40 = pv;  // lanes >= 40 already zero
#pragma unroll
  for (int off = 32; off; off >>= 1) {
    z10 += __shfl_xor(z10, off);
    z20 += __shfl_xor(z20, off);
    z40 += __shfl_xor(z40, off);
  }

  float T[3], wcut[3], iZ[3];
  const int kk3[3] = {10, 20, 40};
#pragma unroll
  for (int s3 = 0; s3 < 3; s3++) {
    int k = kk3[s3];
    if (!special || k <= c) {
      unsigned long long sk = shfl64get(s0, k - 1);
      T[s3] = k2f((unsigned)(sk >> 32));
      wcut[s3] = (float)(~(unsigned)sk);  // index of last admitted tied element
      float Zk = (s3 == 0) ? z10 : ((s3 == 1) ? z20 : z40);
      iZ[s3] = 1.f / Zk;
    } else {
      // k-th largest falls inside the tie cluster at key K (value vt)
      int r = k - c;  // admitted tied elements (lowest indices first)
      float vt = k2f(K);
      T[s3] = vt;
      int lo2 = -1, hi2 = 1023;
      while (hi2 - lo2 > 1) {
        int mid = (lo2 + hi2) >> 1;
        int cnt = 0;
#pragma unroll
        for (int q = 0; q < 16; q++) {
          int idx = lane * 4 + (q >> 2) * 256 + (q & 3);
          cnt += (ky[q] == K && idx <= mid) ? 1 : 0;
        }
#pragma unroll
        for (int off = 32; off; off >>= 1) cnt += __shfl_xor(cnt, off);
        if (cnt >= r) hi2 = mid; else lo2 = mid;
      }
      wcut[s3] = (float)hi2;
      iZ[s3] = 1.f / (z40 + (float)r * __expf(vt - m));  // z40 == sum over all c candidates
    }
  }

  if (lane == 0) {
    float* sp = stats + (size_t)row * 12;
    float4 w0v = {m, 1.f / zf, T[0], T[1]};
    float4 w1v = {T[2], iZ[0], iZ[1], iZ[2]};
    float4 w2v = {wcut[0], wcut[1], wcut[2], 0.f};
    *(float4*)(sp + 0) = w0v;
    *(float4*)(sp + 4) = w1v;
    *(float4*)(sp + 8) = w2v;
  }
}

// ---------------------------------------------------------------------------
// k_init: out[n,o,w,l] = cb[o] + sum_c D[o,c] * x[n,c,w,l]   (fp32 direct path)
__global__ __launch_bounds__(256) void k_init(const float* __restrict__ x,
                                              const float* __restrict__ D,
                                              const float* __restrict__ cb,
                                              float* __restrict__ out) {
  int b = blockIdx.x;
  int n = b >> 10, w = b & 1023;
  int t = threadIdx.x;
  __shared__ float xs[768];
  __shared__ float Ds[64 * 65];
  __shared__ float cbs[64];
  const float* xb = x + (size_t)n * 786432 + w * 12;
  for (int u = t; u < 768; u += 256) {
    int c = u / 12, l2 = u - c * 12;
    xs[u] = xb[(size_t)c * 12288 + l2];
  }
  for (int u = t; u < 4096; u += 256) Ds[(u >> 6) * 65 + (u & 63)] = D[u];
  if (t < 64) cbs[t] = cb[t];
  __syncthreads();
  float* ob = out + (size_t)n * 786432 + w * 12;
  for (int u = t; u < 768; u += 256) {
    int o = u / 12, l2 = u - o * 12;
    float accv = cbs[o];
    const float* dr = &Ds[o * 65];
#pragma unroll
    for (int c = 0; c < 64; c++) accv += dr[c] * xs[c * 12 + l2];
    ob[(size_t)o * 12288 + l2] = accv;
  }
}

// ---------------------------------------------------------------------------
// k_ybuild: Y[(o*12+l)*12288 + ig*1024 + v] = fp16( sum_c x[n,c,v,l] * G[ig][o][c] )
__global__ __launch_bounds__(256) void k_ybuild(const float* __restrict__ x,
                                                const unsigned short* __restrict__ Gt,
                                                unsigned short* __restrict__ Y,
                                                int s) {
  int b = blockIdx.x;
  int nc = b / 576;
  int rem2 = b - nc * 576;
  int mt = rem2 / 6, nt = rem2 - (rem2 / 6) * 6;
  int n = s + nc;
  int l = mt >> 3;
  int v0 = (mt & 7) << 7;

  __shared__ __align__(16) char smem[34816];
  unsigned short(*A2)[128][32] = (unsigned short(*)[128][32])smem;
  unsigned short(*B2)[128][32] = (unsigned short(*)[128][32])(smem + 16384);
  unsigned short(*R)[136] = (unsigned short(*)[136])smem;

  int t = threadIdx.x;
  int lane = t & 63, wid = t >> 6;
  int wm = (wid >> 1) * 64, wn = (wid & 1) * 64;

  // stage A: x[n][c][v0+mloc][l] for c in [half*32, half*32+32)
  {
    int mloc = t >> 1, half = t & 1;
    const float* xp = x + (size_t)n * 786432 + (size_t)(half * 32) * 12288 + (size_t)(v0 + mloc) * 12 + l;
#pragma unroll
    for (int sg = 0; sg < 4; sg++) {
      unsigned q0 = f2h(xp[(size_t)(sg * 8 + 0) * 12288]) | ((unsigned)f2h(xp[(size_t)(sg * 8 + 1) * 12288]) << 16);
      unsigned q1 = f2h(xp[(size_t)(sg * 8 + 2) * 12288]) | ((unsigned)f2h(xp[(size_t)(sg * 8 + 3) * 12288]) << 16);
      unsigned q2 = f2h(xp[(size_t)(sg * 8 + 4) * 12288]) | ((unsigned)f2h(xp[(size_t)(sg * 8 + 5) * 12288]) << 16);
      unsigned q3 = f2h(xp[(size_t)(sg * 8 + 6) * 12288]) | ((unsigned)f2h(xp[(size_t)(sg * 8 + 7) * 12288]) << 16);
      uint4 q = {q0, q1, q2, q3};
      *(uint4*)&A2[half][mloc][sg * 8] = q;
    }
  }
  // stage B: Gt rows nt*128..+128
  {
    int row = t >> 1, half = t & 1;
    const unsigned short* gp = Gt + (size_t)(nt * 128 + row) * 64 + half * 32;
#pragma unroll
    for (int sg = 0; sg < 4; sg++)
      *(uint4*)&B2[half][row][sg * 8] = *(const uint4*)(gp + sg * 8);
  }
  __syncthreads();

  f32x4 acc[4][4];
#pragma unroll
  for (int fm = 0; fm < 4; fm++)
#pragma unroll
    for (int fn = 0; fn < 4; fn++) acc[fm][fn] = (f32x4){0.f, 0.f, 0.f, 0.f};

  int ko = (lane >> 4) * 8;
#pragma unroll
  for (int half = 0; half < 2; half++) {
    f16x8 af[4], bfr[4];
#pragma unroll
    for (int fm = 0; fm < 4; fm++) af[fm] = *(const f16x8*)&A2[half][wm + fm * 16 + (lane & 15)][ko];
#pragma unroll
    for (int fn = 0; fn < 4; fn++) bfr[fn] = *(const f16x8*)&B2[half][wn + fn * 16 + (lane & 15)][ko];
#pragma unroll
    for (int fm = 0; fm < 4; fm++)
#pragma unroll
      for (int fn = 0; fn < 4; fn++)
        acc[fm][fn] = __builtin_amdgcn_mfma_f32_16x16x32_f16(af[fm], bfr[fn], acc[fm][fn], 0, 0, 0);
  }
  __syncthreads();

  // reorder into R[col][m] (m = v offset), 4 consecutive rows per frag-reg
#pragma unroll
  for (int fm = 0; fm < 4; fm++)
#pragma unroll
    for (int fn = 0; fn < 4; fn++) {
      int col = wn + fn * 16 + (lane & 15);
      int mrow = wm + fm * 16 + (lane >> 4) * 4;
      unsigned lo = (unsigned)f2h(acc[fm][fn][0]) | ((unsigned)f2h(acc[fm][fn][1]) << 16);
      unsigned hi = (unsigned)f2h(acc[fm][fn][2]) | ((unsigned)f2h(acc[fm][fn][3]) << 16);
      uint2 pk = {lo, hi};
      *(uint2*)&R[col][mrow] = pk;
    }
  __syncthreads();

  // coalesced output: row = ncol-local, 128 v contiguous
  {
    int row = t >> 1, hseg = t & 1;
    int ncol = nt * 128 + row;
    int ig = ncol >> 6, o = ncol & 63;
    size_t gbase = ((size_t)nc * 768 + (size_t)(o * 12 + l)) * 12288 + (size_t)ig * 1024 + v0 + hseg * 64;
#pragma unroll
    for (int sg = 0; sg < 8; sg++)
      *(uint4*)(Y + gbase + sg * 8) = *(const uint4*)&R[row][hseg * 64 + sg * 8];
  }
}

// ---------------------------------------------------------------------------
// k_buildA: A[(nc*1024+w)*12288 + i*4096 + g*1024 + v] = fp16 softmax weights
__global__ __launch_bounds__(256) void k_buildA(const float* __restrict__ support,
                                                const float* __restrict__ stats,
                                                unsigned short* __restrict__ Abuf,
                                                int s) {
  int b = blockIdx.x;
  int nc = b / 3072;
  int rem2 = b - nc * 3072;
  int i = rem2 >> 10;
  int tile = rem2 & 1023;
  int v0 = (tile >> 5) << 5;
  int w0 = (tile & 31) << 5;
  int n = s + nc;
  const float* sup = support + (size_t)(n * 3 + i) * 1024 * 1024;
  const float* stb = stats + (size_t)(n * 3 + i) * 1024 * 12;

  __shared__ float S[32][33];
  __shared__ float st[32][12];
  int t = threadIdx.x;
  {
    int vl = t >> 3, wseg = t & 7;
    const float* p = sup + (size_t)(v0 + vl) * 1024 + w0 + wseg * 4;
    float4 f = *(const float4*)p;
    S[vl][wseg * 4 + 0] = f.x;
    S[vl][wseg * 4 + 1] = f.y;
    S[vl][wseg * 4 + 2] = f.z;
    S[vl][wseg * 4 + 3] = f.w;
  }
  for (int u = t; u < 384; u += 256) {
    int vl = u / 12, q = u - vl * 12;
    st[vl][q] = stb[(size_t)(v0 + vl) * 12 + q];
  }
  __syncthreads();

  int w_loc = t >> 3, vseg = t & 7;
  float wg = (float)(w0 + w_loc);
  unsigned short bv[4][4];
#pragma unroll
  for (int j = 0; j < 4; j++) {
    int vl = vseg * 4 + j;
    float aa = S[vl][w_loc];
    float m = st[vl][0], izf = st[vl][1];
    float T10 = st[vl][2], T20 = st[vl][3], T40 = st[vl][4];
    float iz10 = st[vl][5], iz20 = st[vl][6], iz40 = st[vl][7];
    float w10 = st[vl][8], w20 = st[vl][9], w40 = st[vl][10];
    float ee = __expf(aa - m);
    bool in10 = (aa > T10) || (aa == T10 && wg <= w10);
    bool in20 = (aa > T20) || (aa == T20 && wg <= w20);
    bool in40 = (aa > T40) || (aa == T40 && wg <= w40);
    bv[3][j] = f2h(ee * izf);
    bv[2][j] = f2h(in40 ? ee * iz40 : 0.f);
    bv[1][j] = f2h(in20 ? ee * iz20 : 0.f);
    bv[0][j] = f2h(in10 ? ee * iz10 : 0.f);
  }
  size_t base = ((size_t)nc * 1024 + w0 + w_loc) * 12288 + (size_t)i * 4096 + v0 + vseg * 4;
#pragma unroll
  for (int g = 0; g < 4; g++) {
    uint2 pk;
    pk.x = (unsigned)bv[g][0] | ((unsigned)bv[g][1] << 16);
    pk.y = (unsigned)bv[g][2] | ((unsigned)bv[g][3] << 16);
    *(uint2*)(Abuf + base + (size_t)g * 1024) = pk;
  }
}

// ---------------------------------------------------------------------------
// k_biggemm: OUT[n][w][(o,l)] += sum_k A[w][k] * Y[(o,l)][k]; M=1024, N=768, K=12288
// m97-structure: global_load_lds width-16 direct staging (no reg round-trip,
// no ds_write bank conflicts), 2 barriers per K-step, + XCD-aware block swizzle.
__global__ __launch_bounds__(256) void k_biggemm(const unsigned short* __restrict__ A,
                                                 const unsigned short* __restrict__ Y,
                                                 float* __restrict__ out,
                                                 int s) {
  // XCD swizzle: grid = Cc*48, always % 8 == 0 -> simple bijective remap.
  int b = blockIdx.x;
  int cpx = gridDim.x >> 3;
  b = (b & 7) * cpx + (b >> 3);

  int nc = b / 48;
  int rem2 = b - nc * 48;
  int mt = rem2 / 6, nt = rem2 - (rem2 / 6) * 6;
  int n = s + nc;

  __shared__ __align__(16) unsigned short A3[128][32];
  __shared__ __align__(16) unsigned short B3[128][32];

  int t = threadIdx.x;
  int lane = t & 63, wid = t >> 6;
  int wm = (wid >> 1) * 64, wn = (wid & 1) * 64;

  const unsigned short* Ab = A + (size_t)nc * 12582912 + (size_t)(mt * 128) * 12288;
  const unsigned short* Yb = Y + (size_t)nc * 9437184 + (size_t)(nt * 128) * 12288;

  int srow = t >> 2;
  int scol = (t & 3) * 8;
  const unsigned short* gA0 = Ab + (size_t)srow * 12288 + scol;
  const unsigned short* gA1 = gA0 + (size_t)64 * 12288;
  const unsigned short* gB0 = Yb + (size_t)srow * 12288 + scol;
  const unsigned short* gB1 = gB0 + (size_t)64 * 12288;
  unsigned short* lA0 = &A3[0][0] + (size_t)t * 8;
  unsigned short* lA1 = lA0 + 2048;
  unsigned short* lB0 = &B3[0][0] + (size_t)t * 8;
  unsigned short* lB1 = lB0 + 2048;

  f32x4 acc[4][4];
#pragma unroll
  for (int fm = 0; fm < 4; fm++)
#pragma unroll
    for (int fn = 0; fn < 4; fn++) acc[fm][fn] = (f32x4){0.f, 0.f, 0.f, 0.f};

  int ko = (lane >> 4) * 8;

  for (int kt = 0; kt < 384; kt++) {
    __syncthreads();  // previous step's ds_reads done before DMA overwrites LDS
    gld16(gA0, lA0);
    gld16(gA1, lA1);
    gld16(gB0, lB0);
    gld16(gB1, lB1);
    gA0 += 32; gA1 += 32; gB0 += 32; gB1 += 32;
    __syncthreads();  // vmcnt(0) drain before s_barrier -> tile ready
    f16x8 af[4], bfr[4];
#pragma unroll
    for (int fm = 0; fm < 4; fm++) af[fm] = *(const f16x8*)&A3[wm + fm * 16 + (lane & 15)][ko];
#pragma unroll
    for (int fn = 0; fn < 4; fn++) bfr[fn] = *(const f16x8*)&B3[wn + fn * 16 + (lane & 15)][ko];
#pragma unroll
    for (int fm = 0; fm < 4; fm++)
#pragma unroll
      for (int fn = 0; fn < 4; fn++)
        acc[fm][fn] = __builtin_amdgcn_mfma_f32_16x16x32_f16(af[fm], bfr[fn], acc[fm][fn], 0, 0, 0);
  }

  // epilogue: RMW into out (tiles are exclusive)
  float* ob = out + (size_t)n * 786432;
#pragma unroll
  for (int fn = 0; fn < 4; fn++) {
    int col = nt * 128 + wn + fn * 16 + (lane & 15);  // = o*12 + l
    int oo = col / 12;
    int ll2 = col - oo * 12;
    float* cbase = ob + (size_t)oo * 12288 + ll2;
#pragma unroll
    for (int fm = 0; fm < 4; fm++) {
      int w = mt * 128 + wm + fm * 16 + (lane >> 4) * 4;
      float* p = cbase + (size_t)w * 12;
#pragma unroll
      for (int r = 0; r < 4; r++) p[r * 12] += acc[fm][fn][r];
    }
  }
}

// ---------------------------------------------------------------------------
extern "C" void kernel_launch(void* const* d_in, const int* in_sizes, int n_in,
                              void* d_out, int out_size, void* d_ws, size_t ws_size,
                              hipStream_t stream) {
  const float* x = (const float*)d_in[0];
  const float* support = (const float*)d_in[1];
  const float* W0 = (const float*)d_in[2];
  const float* b0 = (const float*)d_in[3];
  const float* Ws = (const float*)d_in[4];
  const float* bs = (const float*)d_in[5];
  const float* Wf = (const float*)d_in[6];
  const float* bf = (const float*)d_in[7];
  float* out = (float*)d_out;
  char* ws = (char*)d_ws;

  float* stats = (float*)ws;                              // 49152*12*4 = 2,359,296 B
  float* D = (float*)(ws + 2359296);                      // 16,384 B
  float* cb = (float*)(ws + 2375680);                     // 256 B
  unsigned short* Gt = (unsigned short*)(ws + 2375936);   // 98,304 B
  const size_t fixed_end = 2474240;
  const size_t szY = 18874368;  // per n
  const size_t szA = 25165824;  // per n

  int C = 1;
  if (ws_size > fixed_end) {
    size_t remb = ws_size - fixed_end;
    size_t c = remb / (szY + szA);
    if (c > 16) c = 16;
    if (c < 1) c = 1;
    C = (int)c;
  }
  unsigned short* Ybuf = (unsigned short*)(ws + fixed_end);
  unsigned short* Abuf = (unsigned short*)(ws + fixed_end + (size_t)C * szY);

  k_prep<<<13, 256, 0, stream>>>(W0, b0, Ws, bs, Wf, bf, D, cb, Gt);
  k_stats<<<12288, 256, 0, stream>>>(support, stats);
  k_init<<<16384, 256, 0, stream>>>(x, D, cb, out);
  for (int s = 0; s < 16; s += C) {
    int Cc = (16 - s) < C ? (16 - s) : C;
    k_ybuild<<<Cc * 576, 256, 0, stream>>>(x, Gt, Ybuf, s);
    k_buildA<<<Cc * 3072, 256, 0, stream>>>(support, stats, Abuf, s);
    k_biggemm<<<Cc * 48, 256, 0, stream>>>(Abuf, Ybuf, out, s);
  }
}